// Round 6
// baseline (418.753 us; speedup 1.0000x reference)
//
#include <hip/hip_runtime.h>

// WECT, direction-major v2 (R5). 64 dirs = 4 groups x 16 dirs, u8 bins.
// tabq[g*k0 + v] : uint4 (16 bytes) = bins for dirs g*16 + dw*4 + b.
// Per-group table = 3.2MB; g = bid&3 with XCD = bid%8 -> each XCD serves
// exactly one group -> table L2-resident. Edge/tri/weight streams use
// nontemporal loads so they don't evict the table.
// (R4 was LLC line-fetch bound: 38.4M 4B gathers -> 2.5GB line traffic
// at ~7.3TB/s = 337us. R5: 9.6M 16B gathers, L2-resident.)

#define HGT 256
#define NDIR 64
#define NBINS (HGT * NDIR)
#define NG2 4
#define GSZ 16
#define GBINS (GSZ * HGT)  // 4096 per-group bins
#define TPB 512
#define SSLICES 256  // simplex: 1024 blocks
#define VSLICES 128  // vertex:  512 blocks

__global__ void wect_maxnorm(const float* __restrict__ vc, int k0,
                             unsigned* __restrict__ maxbits) {
    float m = 0.f;
    for (int i = blockIdx.x * blockDim.x + threadIdx.x; i < k0;
         i += gridDim.x * blockDim.x) {
        float x = vc[3 * i], y = vc[3 * i + 1], z = vc[3 * i + 2];
        m = fmaxf(m, sqrtf(x * x + y * y + z * z));
    }
    for (int off = 32; off > 0; off >>= 1)
        m = fmaxf(m, __shfl_down(m, off, 64));
    __shared__ float sm[16];
    int wid = threadIdx.x >> 6, lane = threadIdx.x & 63;
    if (lane == 0) sm[wid] = m;
    __syncthreads();
    if (threadIdx.x == 0) {
        float b = sm[0];
        int nw = blockDim.x >> 6;
        for (int w = 1; w < nw; ++w) b = fmaxf(b, sm[w]);
        atomicMax(maxbits, __float_as_uint(b));  // valid: all values >= 0
    }
}

__device__ __forceinline__ int height_bin(float h, float mh, float inv) {
    int idx = (int)ceilf((255.0f * (mh + h)) * inv);
    return min(max(idx, 0), HGT - 1);
}

__device__ __forceinline__ void flush_group(const float* hist, int g,
                                            float* __restrict__ out) {
    for (int t = threadIdx.x; t < GBINS; t += TPB) {
        float v = hist[t];
        if (v != 0.f)
            atomicAdd(&out[(g * GSZ + (t >> 8)) * HGT + (t & 255)], v);
    }
}

__global__ __launch_bounds__(TPB, 6) void wect_vertex_dm(
    const float* __restrict__ vc, const float* __restrict__ vw,
    const float* __restrict__ dirs, int k0,
    const unsigned* __restrict__ maxbits, uint4* __restrict__ tabq,
    float* __restrict__ out) {
    __shared__ float hist[GBINS];
    int tid = threadIdx.x;
    for (int t = tid; t < GBINS; t += TPB) hist[t] = 0.f;
    int g = blockIdx.x & (NG2 - 1);
    int slice = blockIdx.x >> 2;
    float dx[GSZ], dy[GSZ], dz[GSZ];
#pragma unroll
    for (int c = 0; c < GSZ; ++c) {
        int d = g * GSZ + c;
        dx[c] = dirs[3 * d];
        dy[c] = dirs[3 * d + 1];
        dz[c] = dirs[3 * d + 2];
    }
    float mh = __uint_as_float(*maxbits);
    float inv = 1.0f / (2.0f * mh);
    __syncthreads();
    int lo = (int)((long long)k0 * slice / VSLICES);
    int hi = (int)((long long)k0 * (slice + 1) / VSLICES);
    for (int i = lo + tid; i < hi; i += TPB) {
        float x = vc[3 * i], y = vc[3 * i + 1], z = vc[3 * i + 2];
        float w = vw[i];
        unsigned q[4];
#pragma unroll
        for (int dw = 0; dw < 4; ++dw) {
            q[dw] = 0;
#pragma unroll
            for (int b = 0; b < 4; ++b) {
                int c = dw * 4 + b;
                float h = fmaf(x, dx[c], fmaf(y, dy[c], z * dz[c]));
                int bin = height_bin(h, mh, inv);
                q[dw] |= (unsigned)bin << (8 * b);
                atomicAdd(&hist[c * 256 + bin], w);
            }
        }
        tabq[(size_t)g * k0 + i] = make_uint4(q[0], q[1], q[2], q[3]);
    }
    __syncthreads();
    flush_group(hist, g, out);
}

__global__ __launch_bounds__(TPB, 6) void wect_simplex_dm(
    const int* __restrict__ edges, const float* __restrict__ ew,
    const int* __restrict__ tris, const float* __restrict__ tw, int k1, int k2,
    const uint4* __restrict__ tabq, int k0, float* __restrict__ out) {
    __shared__ float hist[GBINS];
    int tid = threadIdx.x;
    for (int t = tid; t < GBINS; t += TPB) hist[t] = 0.f;
    int g = blockIdx.x & (NG2 - 1);
    int slice = blockIdx.x >> 2;
    const uint4* tab = tabq + (size_t)g * k0;
    __syncthreads();

    // ---- edges: +w, max over 2 endpoints, U=4 ----
    {
        int lo = (int)((long long)k1 * slice / SSLICES);
        int hi = (int)((long long)k1 * (slice + 1) / SSLICES);
        for (int base = lo + tid; base < hi; base += TPB * 4) {
            int ii[4];
            long long ep[4];
            float w[4];
#pragma unroll
            for (int j = 0; j < 4; ++j) {
                ii[j] = base + j * TPB;
                if (ii[j] < hi) {
                    ep[j] = __builtin_nontemporal_load(
                        (const long long*)edges + ii[j]);
                    w[j] = __builtin_nontemporal_load(ew + ii[j]);
                }
            }
            uint4 qa[4], qb[4];
#pragma unroll
            for (int j = 0; j < 4; ++j)
                if (ii[j] < hi) {
                    int va = (int)(ep[j] & 0xffffffffLL);
                    int vb = (int)(ep[j] >> 32);
                    qa[j] = tab[va];
                    qb[j] = tab[vb];
                }
#pragma unroll
            for (int j = 0; j < 4; ++j)
                if (ii[j] < hi) {
                    unsigned pa[4] = {qa[j].x, qa[j].y, qa[j].z, qa[j].w};
                    unsigned pb[4] = {qb[j].x, qb[j].y, qb[j].z, qb[j].w};
#pragma unroll
                    for (int dw = 0; dw < 4; ++dw)
#pragma unroll
                        for (int b = 0; b < 4; ++b) {
                            int sh = 8 * b;
                            int m = max((int)((pa[dw] >> sh) & 255),
                                        (int)((pb[dw] >> sh) & 255));
                            atomicAdd(&hist[(dw * 4 + b) * 256 + m], w[j]);
                        }
                }
        }
    }

    // ---- triangles: -w, max over 3 endpoints, U=2 ----
    {
        int lo = (int)((long long)k2 * slice / SSLICES);
        int hi = (int)((long long)k2 * (slice + 1) / SSLICES);
        for (int base = lo + tid; base < hi; base += TPB * 2) {
            int ii[2], v0[2], v1[2], v2[2];
            float w[2];
#pragma unroll
            for (int j = 0; j < 2; ++j) {
                ii[j] = base + j * TPB;
                if (ii[j] < hi) {
                    v0[j] = __builtin_nontemporal_load(tris + 3 * ii[j]);
                    v1[j] = __builtin_nontemporal_load(tris + 3 * ii[j] + 1);
                    v2[j] = __builtin_nontemporal_load(tris + 3 * ii[j] + 2);
                    w[j] = __builtin_nontemporal_load(tw + ii[j]);
                }
            }
            uint4 qa[2], qb[2], qc[2];
#pragma unroll
            for (int j = 0; j < 2; ++j)
                if (ii[j] < hi) {
                    qa[j] = tab[v0[j]];
                    qb[j] = tab[v1[j]];
                    qc[j] = tab[v2[j]];
                }
#pragma unroll
            for (int j = 0; j < 2; ++j)
                if (ii[j] < hi) {
                    unsigned pa[4] = {qa[j].x, qa[j].y, qa[j].z, qa[j].w};
                    unsigned pb[4] = {qb[j].x, qb[j].y, qb[j].z, qb[j].w};
                    unsigned pc[4] = {qc[j].x, qc[j].y, qc[j].z, qc[j].w};
#pragma unroll
                    for (int dw = 0; dw < 4; ++dw)
#pragma unroll
                        for (int b = 0; b < 4; ++b) {
                            int sh = 8 * b;
                            int m = max((int)((pa[dw] >> sh) & 255),
                                        max((int)((pb[dw] >> sh) & 255),
                                            (int)((pc[dw] >> sh) & 255)));
                            atomicAdd(&hist[(dw * 4 + b) * 256 + m], -w[j]);
                        }
                }
        }
    }

    __syncthreads();
    flush_group(hist, g, out);
}

// ---------------- fallback kernels (no workspace table) ----------------

__global__ __launch_bounds__(512) void wect_simplex_rec(
    const int* __restrict__ edges, const float* __restrict__ ew,
    const int* __restrict__ tris, const float* __restrict__ tw, int k1, int k2,
    const float* __restrict__ vc, const float* __restrict__ dirs,
    const unsigned* __restrict__ maxbits, float* __restrict__ out) {
    __shared__ float hist[NBINS];
    for (int i = threadIdx.x; i < NBINS; i += blockDim.x) hist[i] = 0.f;
    int lane = threadIdx.x & 63;
    float d0 = dirs[lane * 3], d1 = dirs[lane * 3 + 1], d2 = dirs[lane * 3 + 2];
    float mh = __uint_as_float(*maxbits);
    float inv = 1.0f / (2.0f * mh);
    __syncthreads();
    int wid = (blockIdx.x * blockDim.x + threadIdx.x) >> 6;
    int nw = (gridDim.x * blockDim.x) >> 6;
    int total = k1 + k2;
    for (int s = wid; s < total; s += nw) {
        int idx;
        float w;
        if (s < k1) {
            int v0 = edges[2 * s], v1 = edges[2 * s + 1];
            float h0 = vc[3 * v0] * d0 + vc[3 * v0 + 1] * d1 + vc[3 * v0 + 2] * d2;
            float h1 = vc[3 * v1] * d0 + vc[3 * v1 + 1] * d1 + vc[3 * v1 + 2] * d2;
            idx = max(height_bin(h0, mh, inv), height_bin(h1, mh, inv));
            w = ew[s];
        } else {
            int t = s - k1;
            int v0 = tris[3 * t], v1 = tris[3 * t + 1], v2 = tris[3 * t + 2];
            float h0 = vc[3 * v0] * d0 + vc[3 * v0 + 1] * d1 + vc[3 * v0 + 2] * d2;
            float h1 = vc[3 * v1] * d0 + vc[3 * v1 + 1] * d1 + vc[3 * v1 + 2] * d2;
            float h2 = vc[3 * v2] * d0 + vc[3 * v2 + 1] * d1 + vc[3 * v2 + 2] * d2;
            idx = max(height_bin(h0, mh, inv),
                      max(height_bin(h1, mh, inv), height_bin(h2, mh, inv)));
            w = -tw[t];
        }
        atomicAdd(&hist[idx * NDIR + lane], w);
    }
    __syncthreads();
    for (int i = threadIdx.x; i < NBINS; i += blockDim.x) {
        float v = hist[i];
        if (v != 0.f) atomicAdd(&out[(i & 63) * HGT + (i >> 6)], v);
    }
}

__global__ __launch_bounds__(512) void wect_vertex_rec(
    const float* __restrict__ vc, const float* __restrict__ vw,
    const float* __restrict__ dirs, int k0,
    const unsigned* __restrict__ maxbits, float* __restrict__ out) {
    __shared__ float hist[NBINS];
    for (int i = threadIdx.x; i < NBINS; i += blockDim.x) hist[i] = 0.f;
    int lane = threadIdx.x & 63;
    float d0 = dirs[lane * 3], d1 = dirs[lane * 3 + 1], d2 = dirs[lane * 3 + 2];
    float mh = __uint_as_float(*maxbits);
    float inv = 1.0f / (2.0f * mh);
    __syncthreads();
    int wid = (blockIdx.x * blockDim.x + threadIdx.x) >> 6;
    int nw = (gridDim.x * blockDim.x) >> 6;
    for (int k = wid; k < k0; k += nw) {
        float h = vc[3 * k] * d0 + vc[3 * k + 1] * d1 + vc[3 * k + 2] * d2;
        int idx = height_bin(h, mh, inv);
        atomicAdd(&hist[idx * NDIR + lane], vw[k]);
    }
    __syncthreads();
    for (int i = threadIdx.x; i < NBINS; i += blockDim.x) {
        float v = hist[i];
        if (v != 0.f) atomicAdd(&out[(i & 63) * HGT + (i >> 6)], v);
    }
}

__global__ void wect_cumsum(float* __restrict__ out) {
    // one wave (64 lanes) per direction row of 256 floats
    int lane = threadIdx.x;
    float4* row = (float4*)out + (size_t)blockIdx.x * 64;
    float4 v = row[lane];
    v.y += v.x;
    v.z += v.y;
    v.w += v.z;
    float s = v.w;
    float mine = s;
    for (int off = 1; off < 64; off <<= 1) {
        float t = __shfl_up(s, off, 64);
        if (lane >= off) s += t;
    }
    float excl = s - mine;
    v.x += excl;
    v.y += excl;
    v.z += excl;
    v.w += excl;
    row[lane] = v;
}

extern "C" void kernel_launch(void* const* d_in, const int* in_sizes, int n_in,
                              void* d_out, int out_size, void* d_ws,
                              size_t ws_size, hipStream_t stream) {
    const float* v_coords = (const float*)d_in[0];
    const float* v_weights = (const float*)d_in[1];
    const int* edges = (const int*)d_in[2];
    const float* e_weights = (const float*)d_in[3];
    const int* tris = (const int*)d_in[4];
    const float* t_weights = (const float*)d_in[5];
    const float* dirs = (const float*)d_in[6];
    // d_in[7] = num_heights (=256, hardcoded as HGT)

    int k0 = in_sizes[0] / 3;
    int k1 = in_sizes[2] / 2;
    int k2 = in_sizes[4] / 3;

    float* out = (float*)d_out;
    unsigned* maxbits = (unsigned*)d_ws;
    uint4* tabq = (uint4*)((char*)d_ws + 64);
    bool have_table = ws_size >= 64 + (size_t)NG2 * k0 * 16;

    (void)hipMemsetAsync(d_ws, 0, 64, stream);
    (void)hipMemsetAsync(d_out, 0, (size_t)NBINS * sizeof(float), stream);

    wect_maxnorm<<<256, 256, 0, stream>>>(v_coords, k0, maxbits);

    if (have_table) {
        wect_vertex_dm<<<NG2 * VSLICES, TPB, 0, stream>>>(
            v_coords, v_weights, dirs, k0, maxbits, tabq, out);
        wect_simplex_dm<<<NG2 * SSLICES, TPB, 0, stream>>>(
            edges, e_weights, tris, t_weights, k1, k2, tabq, k0, out);
    } else {
        wect_vertex_rec<<<512, 512, 0, stream>>>(v_coords, v_weights, dirs, k0,
                                                 maxbits, out);
        wect_simplex_rec<<<512, 512, 0, stream>>>(edges, e_weights, tris,
                                                  t_weights, k1, k2, v_coords,
                                                  dirs, maxbits, out);
    }
    wect_cumsum<<<NDIR, 64, 0, stream>>>(out);
}